// Round 1
// baseline (4439.746 us; speedup 1.0000x reference)
//
#include <hip/hip_runtime.h>

#define D_IN 128
#define D_HID 256
#define D_OUT 128

// ---------------- degree / normalization ----------------

__global__ void k_deg(const int* __restrict__ src, float* __restrict__ deg, int E) {
    int e = blockIdx.x * blockDim.x + threadIdx.x;
    if (e < E) atomicAdd(&deg[src[e]], 1.0f);
}

__global__ void k_dis(float* __restrict__ deg, int n) {
    int i = blockIdx.x * blockDim.x + threadIdx.x;
    if (i < n) {
        float d = deg[i];
        deg[i] = d > 0.f ? rsqrtf(fmaxf(d, 1.0f)) : 0.f;
    }
}

__global__ void k_norm(const int* __restrict__ src, const int* __restrict__ dst,
                       const float* __restrict__ dis, float* __restrict__ norm, int E) {
    int e = blockIdx.x * blockDim.x + threadIdx.x;
    if (e < E) norm[e] = -(dis[src[e]] * dis[dst[e]]);
}

// ---------------- edge aggregation (scatter-add) ----------------
// thread t handles edge e = t/(D/4), 4 consecutive floats. Consecutive lanes
// share an edge -> coalesced float4 gathers of x[src], atomics have locality.

template<int D>
__global__ void k_aggregate(const int* __restrict__ src, const int* __restrict__ dst,
                            const float* __restrict__ norm, const float* __restrict__ xin,
                            float* __restrict__ tx, int E) {
    const int CPE = D / 4;
    int tid = blockIdx.x * blockDim.x + threadIdx.x;
    int e = tid / CPE;
    if (e >= E) return;
    int c = (tid % CPE) * 4;
    int s = src[e], d = dst[e];
    float nv = norm[e];
    float4 xv = *reinterpret_cast<const float4*>(&xin[(long long)s * D + c]);
    float* t = &tx[(long long)d * D + c];
    atomicAdd(&t[0], nv * xv.x);
    atomicAdd(&t[1], nv * xv.y);
    atomicAdd(&t[2], nv * xv.z);
    atomicAdd(&t[3], nv * xv.w);
}

// ---------------- fused GEMM ----------------
// C[nrows, dout] = act( A1@W0 (+ A2@W1) (+ ADDV) (+ bias) )
// 64x64 tile, BK=32, 256 threads, each computes 4x4.

template<int K, bool RELU, bool HAS_B2, bool HAS_ADD, bool HAS_BIAS>
__global__ __launch_bounds__(256) void k_gemm(
        const float* __restrict__ A1, const float* __restrict__ W0,
        const float* __restrict__ A2, const float* __restrict__ W1,
        const float* __restrict__ ADDV, const float* __restrict__ bias,
        float* __restrict__ C, int nrows, int dout) {
    const int BM = 64, BN = 64, BK = 32;
    __shared__ float As[BM][BK + 1];
    __shared__ float Ws[BK][BN];
    int tid = threadIdx.x;
    int tx = tid & 15, ty = tid >> 4;
    int rowBase = blockIdx.x * BM;
    int colBase = blockIdx.y * BN;
    float acc[4][4] = {};

    const int npass = HAS_B2 ? 2 : 1;
    for (int pass = 0; pass < npass; ++pass) {
        const float* A = (pass == 0) ? A1 : A2;
        const float* W = (pass == 0) ? W0 : W1;
        for (int k0 = 0; k0 < K; k0 += BK) {
            // stage A tile: 64 rows x 32 k (512 float4, 2/thread)
            #pragma unroll
            for (int l = 0; l < 2; ++l) {
                int f = tid + l * 256;
                int r = f >> 3;
                int j4 = (f & 7) * 4;
                int gr = rowBase + r;
                if (gr >= nrows) gr = nrows - 1;   // clamp; result discarded on store
                float4 v = *reinterpret_cast<const float4*>(&A[(long long)gr * K + k0 + j4]);
                As[r][j4 + 0] = v.x; As[r][j4 + 1] = v.y;
                As[r][j4 + 2] = v.z; As[r][j4 + 3] = v.w;
            }
            // stage W tile: 32 k x 64 cols
            #pragma unroll
            for (int l = 0; l < 2; ++l) {
                int f = tid + l * 256;
                int r = f >> 4;
                int j4 = (f & 15) * 4;
                float4 v = *reinterpret_cast<const float4*>(&W[(long long)(k0 + r) * dout + colBase + j4]);
                *reinterpret_cast<float4*>(&Ws[r][j4]) = v;
            }
            __syncthreads();
            #pragma unroll
            for (int kk = 0; kk < BK; ++kk) {
                float a[4];
                #pragma unroll
                for (int i = 0; i < 4; ++i) a[i] = As[ty * 4 + i][kk];
                float4 w = *reinterpret_cast<const float4*>(&Ws[kk][tx * 4]);
                float wv[4] = {w.x, w.y, w.z, w.w};
                #pragma unroll
                for (int i = 0; i < 4; ++i)
                    #pragma unroll
                    for (int j = 0; j < 4; ++j)
                        acc[i][j] += a[i] * wv[j];
            }
            __syncthreads();
        }
    }

    // epilogue
    #pragma unroll
    for (int i = 0; i < 4; ++i) {
        int r = rowBase + ty * 4 + i;
        if (r < nrows) {
            int cb = colBase + tx * 4;
            float v[4];
            #pragma unroll
            for (int j = 0; j < 4; ++j) v[j] = acc[i][j];
            if (HAS_BIAS) {
                #pragma unroll
                for (int j = 0; j < 4; ++j) v[j] += bias[cb + j];
            }
            if (HAS_ADD) {
                float4 ad = *reinterpret_cast<const float4*>(&ADDV[(long long)r * dout + cb]);
                v[0] += ad.x; v[1] += ad.y; v[2] += ad.z; v[3] += ad.w;
            }
            if (RELU) {
                #pragma unroll
                for (int j = 0; j < 4; ++j) v[j] = fmaxf(v[j], 0.f);
            }
            float4 o; o.x = v[0]; o.y = v[1]; o.z = v[2]; o.w = v[3];
            *reinterpret_cast<float4*>(&C[(long long)r * dout + cb]) = o;
        }
    }
}

// ---------------- launch ----------------

extern "C" void kernel_launch(void* const* d_in, const int* in_sizes, int n_in,
                              void* d_out, int out_size, void* d_ws, size_t ws_size,
                              hipStream_t stream) {
    const float* x   = (const float*)d_in[0];
    const int*   ei  = (const int*)d_in[1];
    const float* W01 = (const float*)d_in[3];
    const float* W11 = (const float*)d_in[4];
    const float* b1  = (const float*)d_in[5];
    const float* W02 = (const float*)d_in[6];
    const float* W12 = (const float*)d_in[7];
    const float* b2  = (const float*)d_in[8];
    const float* W03 = (const float*)d_in[9];
    const float* W13 = (const float*)d_in[10];
    const float* b3  = (const float*)d_in[11];
    float* out = (float*)d_out;

    const int n = in_sizes[0] / D_IN;   // 10000
    const int E = in_sizes[1] / 2;      // 640000
    const int* src = ei;
    const int* dst = ei + E;

    float* ws   = (float*)d_ws;
    float* dis  = ws;                       // n (padded to 10240)
    float* norm = ws + 10240;               // E
    float* tx   = norm + E;                 // n*256
    float* h1   = tx + (size_t)n * D_HID;   // n*256
    float* h2   = h1 + (size_t)n * D_HID;   // n*256
    float* y3   = h1;                       // reuse h1 after layer 2

    const int gx = (n + 63) / 64;           // 157

    // normalization
    hipMemsetAsync(dis, 0, (size_t)n * sizeof(float), stream);
    k_deg<<<(E + 255) / 256, 256, 0, stream>>>(src, dis, E);
    k_dis<<<(n + 255) / 256, 256, 0, stream>>>(dis, n);
    k_norm<<<(E + 255) / 256, 256, 0, stream>>>(src, dst, dis, norm, E);

    // ---- layer 1: h1 = relu(x@W01 + (A x)@W11 + b1) ----
    hipMemsetAsync(tx, 0, (size_t)n * D_IN * sizeof(float), stream);
    {
        int tot = E * (D_IN / 4);
        k_aggregate<D_IN><<<(tot + 255) / 256, 256, 0, stream>>>(src, dst, norm, x, tx, E);
    }
    k_gemm<D_IN, true, true, false, true><<<dim3(gx, D_HID / 64), 256, 0, stream>>>(
        x, W01, tx, W11, nullptr, b1, h1, n, D_HID);

    // ---- layer 2: h2 = relu(h1@W02 + (A h1)@W12 + b2) ----
    hipMemsetAsync(tx, 0, (size_t)n * D_HID * sizeof(float), stream);
    {
        int tot = E * (D_HID / 4);
        k_aggregate<D_HID><<<(tot + 255) / 256, 256, 0, stream>>>(src, dst, norm, h1, tx, E);
    }
    k_gemm<D_HID, true, true, false, true><<<dim3(gx, D_HID / 64), 256, 0, stream>>>(
        h1, W02, tx, W12, nullptr, b2, h2, n, D_HID);

    // ---- layer 3: out = h2@W03 + A (h2@W13) + b3 ----
    k_gemm<D_HID, false, false, false, false><<<dim3(gx, D_OUT / 64), 256, 0, stream>>>(
        h2, W13, nullptr, nullptr, nullptr, nullptr, y3, n, D_OUT);
    hipMemsetAsync(tx, 0, (size_t)n * D_OUT * sizeof(float), stream);
    {
        int tot = E * (D_OUT / 4);
        k_aggregate<D_OUT><<<(tot + 255) / 256, 256, 0, stream>>>(src, dst, norm, y3, tx, E);
    }
    k_gemm<D_HID, false, false, true, true><<<dim3(gx, D_OUT / 64), 256, 0, stream>>>(
        h2, W03, nullptr, nullptr, tx, b3, out, n, D_OUT);
}

// Round 2
// 402.560 us; speedup vs baseline: 11.0288x; 11.0288x over previous
//
#include <hip/hip_runtime.h>

#define D_IN 128
#define D_HID 256
#define D_OUT 128

// ---------------- degree (over src) + histogram (over dst) ----------------

__global__ void k_deg_hist(const int* __restrict__ src, const int* __restrict__ dst,
                           float* __restrict__ deg, int* __restrict__ cnt, int E) {
    int e = blockIdx.x * blockDim.x + threadIdx.x;
    if (e < E) {
        atomicAdd(&deg[src[e]], 1.0f);
        atomicAdd(&cnt[dst[e]], 1);
    }
}

__global__ void k_dis(float* __restrict__ deg, int n) {
    int i = blockIdx.x * blockDim.x + threadIdx.x;
    if (i < n) {
        float d = deg[i];
        deg[i] = d > 0.f ? rsqrtf(fmaxf(d, 1.0f)) : 0.f;
    }
}

// ---------------- exclusive scan (single block, n ~ 10000) ----------------

__global__ void k_scan(const int* __restrict__ cnt, int* __restrict__ off,
                       int* __restrict__ cntrun, int n, int E) {
    __shared__ int sums[256];
    int t = threadIdx.x;
    int chunk = (n + 255) / 256;
    int beg = t * chunk;
    int end = beg + chunk; if (end > n) end = n;
    int s = 0;
    for (int i = beg; i < end; ++i) s += cnt[i];
    sums[t] = s;
    __syncthreads();
    if (t == 0) {
        int running = 0;
        for (int i = 0; i < 256; ++i) { int tmp = sums[i]; sums[i] = running; running += tmp; }
        off[n] = E;
    }
    __syncthreads();
    int pre = sums[t];
    for (int i = beg; i < end; ++i) {
        off[i] = pre;
        cntrun[i] = pre;
        pre += cnt[i];
    }
}

// ---------------- scatter edges into dst-sorted order ----------------

__global__ void k_scatter(const int* __restrict__ src, const int* __restrict__ dst,
                          const float* __restrict__ dis, int* __restrict__ cntrun,
                          int* __restrict__ srcs, float* __restrict__ norms, int E) {
    int e = blockIdx.x * blockDim.x + threadIdx.x;
    if (e < E) {
        int s = src[e], d = dst[e];
        int pos = atomicAdd(&cntrun[d], 1);
        srcs[pos] = s;
        norms[pos] = -(dis[s] * dis[d]);
    }
}

// ---------------- CSR gather-aggregate: out[d] = sum norm*x[src] ----------------
// TPN = D/4 lanes per node; each lane owns 4 consecutive columns (float4).

template<int D>
__global__ __launch_bounds__(256) void k_agg(const int* __restrict__ off,
                                             const int* __restrict__ srcs,
                                             const float* __restrict__ norms,
                                             const float* __restrict__ xin,
                                             float* __restrict__ outx, int n) {
    const int TPN = D / 4;
    const int NPB = 256 / TPN;
    int tid = threadIdx.x;
    int node = blockIdx.x * NPB + tid / TPN;
    if (node >= n) return;
    int c = (tid % TPN) * 4;
    int i = off[node], end = off[node + 1];
    float ax = 0.f, ay = 0.f, az = 0.f, aw = 0.f;
    // unroll by 2 for a little ILP on the dependent gather chain
    for (; i + 1 < end; i += 2) {
        int s0 = srcs[i],     s1 = srcs[i + 1];
        float n0 = norms[i],  n1 = norms[i + 1];
        float4 v0 = *reinterpret_cast<const float4*>(&xin[(size_t)s0 * D + c]);
        float4 v1 = *reinterpret_cast<const float4*>(&xin[(size_t)s1 * D + c]);
        ax += n0 * v0.x + n1 * v1.x;
        ay += n0 * v0.y + n1 * v1.y;
        az += n0 * v0.z + n1 * v1.z;
        aw += n0 * v0.w + n1 * v1.w;
    }
    if (i < end) {
        int s0 = srcs[i]; float n0 = norms[i];
        float4 v0 = *reinterpret_cast<const float4*>(&xin[(size_t)s0 * D + c]);
        ax += n0 * v0.x; ay += n0 * v0.y; az += n0 * v0.z; aw += n0 * v0.w;
    }
    float4 o; o.x = ax; o.y = ay; o.z = az; o.w = aw;
    *reinterpret_cast<float4*>(&outx[(size_t)node * D + c]) = o;
}

// ---------------- fused GEMM ----------------
// C[nrows, dout] = act( A1@W0 (+ A2@W1) (+ ADDV) (+ bias) )

template<int K, bool RELU, bool HAS_B2, bool HAS_ADD, bool HAS_BIAS>
__global__ __launch_bounds__(256) void k_gemm(
        const float* __restrict__ A1, const float* __restrict__ W0,
        const float* __restrict__ A2, const float* __restrict__ W1,
        const float* __restrict__ ADDV, const float* __restrict__ bias,
        float* __restrict__ C, int nrows, int dout) {
    const int BM = 64, BN = 64, BK = 32;
    __shared__ float As[BM][BK + 1];
    __shared__ float Ws[BK][BN];
    int tid = threadIdx.x;
    int tx = tid & 15, ty = tid >> 4;
    int rowBase = blockIdx.x * BM;
    int colBase = blockIdx.y * BN;
    float acc[4][4] = {};

    const int npass = HAS_B2 ? 2 : 1;
    for (int pass = 0; pass < npass; ++pass) {
        const float* A = (pass == 0) ? A1 : A2;
        const float* W = (pass == 0) ? W0 : W1;
        for (int k0 = 0; k0 < K; k0 += BK) {
            #pragma unroll
            for (int l = 0; l < 2; ++l) {
                int f = tid + l * 256;
                int r = f >> 3;
                int j4 = (f & 7) * 4;
                int gr = rowBase + r;
                if (gr >= nrows) gr = nrows - 1;
                float4 v = *reinterpret_cast<const float4*>(&A[(size_t)gr * K + k0 + j4]);
                As[r][j4 + 0] = v.x; As[r][j4 + 1] = v.y;
                As[r][j4 + 2] = v.z; As[r][j4 + 3] = v.w;
            }
            #pragma unroll
            for (int l = 0; l < 2; ++l) {
                int f = tid + l * 256;
                int r = f >> 4;
                int j4 = (f & 15) * 4;
                float4 v = *reinterpret_cast<const float4*>(&W[(size_t)(k0 + r) * dout + colBase + j4]);
                *reinterpret_cast<float4*>(&Ws[r][j4]) = v;
            }
            __syncthreads();
            #pragma unroll
            for (int kk = 0; kk < BK; ++kk) {
                float a[4];
                #pragma unroll
                for (int i = 0; i < 4; ++i) a[i] = As[ty * 4 + i][kk];
                float4 w = *reinterpret_cast<const float4*>(&Ws[kk][tx * 4]);
                float wv[4] = {w.x, w.y, w.z, w.w};
                #pragma unroll
                for (int i = 0; i < 4; ++i)
                    #pragma unroll
                    for (int j = 0; j < 4; ++j)
                        acc[i][j] += a[i] * wv[j];
            }
            __syncthreads();
        }
    }

    #pragma unroll
    for (int i = 0; i < 4; ++i) {
        int r = rowBase + ty * 4 + i;
        if (r < nrows) {
            int cb = colBase + tx * 4;
            float v[4];
            #pragma unroll
            for (int j = 0; j < 4; ++j) v[j] = acc[i][j];
            if (HAS_BIAS) {
                #pragma unroll
                for (int j = 0; j < 4; ++j) v[j] += bias[cb + j];
            }
            if (HAS_ADD) {
                float4 ad = *reinterpret_cast<const float4*>(&ADDV[(size_t)r * dout + cb]);
                v[0] += ad.x; v[1] += ad.y; v[2] += ad.z; v[3] += ad.w;
            }
            if (RELU) {
                #pragma unroll
                for (int j = 0; j < 4; ++j) v[j] = fmaxf(v[j], 0.f);
            }
            float4 o; o.x = v[0]; o.y = v[1]; o.z = v[2]; o.w = v[3];
            *reinterpret_cast<float4*>(&C[(size_t)r * dout + cb]) = o;
        }
    }
}

// ---------------- launch ----------------

extern "C" void kernel_launch(void* const* d_in, const int* in_sizes, int n_in,
                              void* d_out, int out_size, void* d_ws, size_t ws_size,
                              hipStream_t stream) {
    const float* x   = (const float*)d_in[0];
    const int*   ei  = (const int*)d_in[1];
    const float* W01 = (const float*)d_in[3];
    const float* W11 = (const float*)d_in[4];
    const float* b1  = (const float*)d_in[5];
    const float* W02 = (const float*)d_in[6];
    const float* W12 = (const float*)d_in[7];
    const float* b2  = (const float*)d_in[8];
    const float* W03 = (const float*)d_in[9];
    const float* W13 = (const float*)d_in[10];
    const float* b3  = (const float*)d_in[11];
    float* out = (float*)d_out;

    const int n = in_sizes[0] / D_IN;   // 10000
    const int E = in_sizes[1] / 2;      // 640000
    const int* src = ei;
    const int* dst = ei + E;

    char* wsb = (char*)d_ws;
    float* dis    = (float*)wsb;                 wsb += 10496 * 4;
    int*   cnt    = (int*)wsb;                   wsb += 10496 * 4;
    int*   off    = (int*)wsb;                   wsb += 10496 * 4;
    int*   cntrun = (int*)wsb;                   wsb += 10496 * 4;
    int*   srcs   = (int*)wsb;                   wsb += (size_t)E * 4;
    float* norms  = (float*)wsb;                 wsb += (size_t)E * 4;
    float* tx     = (float*)wsb;                 wsb += (size_t)n * D_HID * 4;
    float* h1     = (float*)wsb;                 wsb += (size_t)n * D_HID * 4;
    float* h2     = (float*)wsb;                 wsb += (size_t)n * D_HID * 4;
    float* y3     = h1;                          // reuse h1 after layer 2

    const int gx = (n + 63) / 64;

    // ---- normalization + CSR build (dst-sorted edges) ----
    hipMemsetAsync(dis, 0, (size_t)n * sizeof(float), stream);
    hipMemsetAsync(cnt, 0, (size_t)n * sizeof(int), stream);
    k_deg_hist<<<(E + 255) / 256, 256, 0, stream>>>(src, dst, dis, cnt, E);
    k_dis<<<(n + 255) / 256, 256, 0, stream>>>(dis, n);
    k_scan<<<1, 256, 0, stream>>>(cnt, off, cntrun, n, E);
    k_scatter<<<(E + 255) / 256, 256, 0, stream>>>(src, dst, dis, cntrun, srcs, norms, E);

    // ---- layer 1: h1 = relu(x@W01 + (A x)@W11 + b1) ----
    k_agg<D_IN><<<(n + 7) / 8, 256, 0, stream>>>(off, srcs, norms, x, tx, n);
    k_gemm<D_IN, true, true, false, true><<<dim3(gx, D_HID / 64), 256, 0, stream>>>(
        x, W01, tx, W11, nullptr, b1, h1, n, D_HID);

    // ---- layer 2: h2 = relu(h1@W02 + (A h1)@W12 + b2) ----
    k_agg<D_HID><<<(n + 3) / 4, 256, 0, stream>>>(off, srcs, norms, h1, tx, n);
    k_gemm<D_HID, true, true, false, true><<<dim3(gx, D_HID / 64), 256, 0, stream>>>(
        h1, W02, tx, W12, nullptr, b2, h2, n, D_HID);

    // ---- layer 3: out = h2@W03 + A (h2@W13) + b3 ----
    k_gemm<D_HID, false, false, false, false><<<dim3(gx, D_OUT / 64), 256, 0, stream>>>(
        h2, W13, nullptr, nullptr, nullptr, nullptr, y3, n, D_OUT);
    k_agg<D_OUT><<<(n + 7) / 8, 256, 0, stream>>>(off, srcs, norms, y3, tx, n);
    k_gemm<D_HID, false, false, true, true><<<dim3(gx, D_OUT / 64), 256, 0, stream>>>(
        h2, W03, nullptr, nullptr, tx, b3, out, n, D_OUT);
}

// Round 3
// 359.796 us; speedup vs baseline: 12.3396x; 1.1189x over previous
//
#include <hip/hip_runtime.h>

#define D_IN 128
#define D_HID 256
#define D_OUT 128

typedef __attribute__((ext_vector_type(8))) unsigned short ushort8v;
typedef __attribute__((ext_vector_type(4))) unsigned short ushort4v;

__device__ __forceinline__ unsigned short f2bf(float f) {
    unsigned u = __float_as_uint(f);
    unsigned r = (u + 0x7fffu + ((u >> 16) & 1u)) >> 16;
    return (unsigned short)r;
}
__device__ __forceinline__ float bf2f(unsigned short b) {
    return __uint_as_float((unsigned)b << 16);
}

// ---------------- degree (over src) + histogram (over dst) ----------------

__global__ void k_deg_hist(const int* __restrict__ src, const int* __restrict__ dst,
                           float* __restrict__ deg, int* __restrict__ cnt, int E) {
    int e = blockIdx.x * blockDim.x + threadIdx.x;
    if (e < E) {
        atomicAdd(&deg[src[e]], 1.0f);
        atomicAdd(&cnt[dst[e]], 1);
    }
}

__global__ void k_dis(float* __restrict__ deg, int n) {
    int i = blockIdx.x * blockDim.x + threadIdx.x;
    if (i < n) {
        float d = deg[i];
        deg[i] = d > 0.f ? rsqrtf(fmaxf(d, 1.0f)) : 0.f;
    }
}

// ---------------- exclusive scan (single block) ----------------

__global__ void k_scan(const int* __restrict__ cnt, int* __restrict__ off,
                       int* __restrict__ cntrun, int n, int E) {
    __shared__ int sums[256];
    int t = threadIdx.x;
    int chunk = (n + 255) / 256;
    int beg = t * chunk;
    int end = beg + chunk; if (end > n) end = n;
    int s = 0;
    for (int i = beg; i < end; ++i) s += cnt[i];
    sums[t] = s;
    __syncthreads();
    if (t == 0) {
        int running = 0;
        for (int i = 0; i < 256; ++i) { int tmp = sums[i]; sums[i] = running; running += tmp; }
        off[n] = E;
    }
    __syncthreads();
    int pre = sums[t];
    for (int i = beg; i < end; ++i) {
        off[i] = pre;
        cntrun[i] = pre;
        pre += cnt[i];
    }
}

// ---------------- scatter edges into dst-sorted order ----------------

__global__ void k_scatter(const int* __restrict__ src, const int* __restrict__ dst,
                          const float* __restrict__ dis, int* __restrict__ cntrun,
                          int* __restrict__ srcs, float* __restrict__ norms, int E) {
    int e = blockIdx.x * blockDim.x + threadIdx.x;
    if (e < E) {
        int s = src[e], d = dst[e];
        int pos = atomicAdd(&cntrun[d], 1);
        srcs[pos] = s;
        norms[pos] = -(dis[s] * dis[d]);
    }
}

// ---------------- fp32 -> bf16 convert ----------------

__global__ void k_f2bf(const float* __restrict__ in, unsigned short* __restrict__ out, int nElem) {
    int i = (blockIdx.x * blockDim.x + threadIdx.x) * 4;
    if (i < nElem) {
        float4 v = *reinterpret_cast<const float4*>(&in[i]);
        ushort4v o;
        o[0] = f2bf(v.x); o[1] = f2bf(v.y); o[2] = f2bf(v.z); o[3] = f2bf(v.w);
        *reinterpret_cast<ushort4v*>(&out[i]) = o;
    }
}

// ---------------- CSR gather-aggregate, bf16 input, column-chunked ----------------
// CHUNK=128 cols per y-block: bf16 working set n*128*2 = 2.56 MB fits per-XCD L2.
// 16 lanes per node, 8 bf16 (16 B) per lane. fp32 accumulate.

template<int D, int CHUNK>
__global__ __launch_bounds__(256) void k_agg_bf(const int* __restrict__ off,
                                                const int* __restrict__ srcs,
                                                const float* __restrict__ norms,
                                                const unsigned short* __restrict__ xb,
                                                float* __restrict__ outx, int n) {
    const int TPN = CHUNK / 8;       // 16 lanes per node
    const int NPB = 256 / TPN;       // 16 nodes per block
    int tid = threadIdx.x;
    int node = blockIdx.x * NPB + tid / TPN;
    if (node >= n) return;
    int cbase = blockIdx.y * CHUNK + (tid % TPN) * 8;
    int i = off[node], end = off[node + 1];
    float acc[8] = {};
    for (; i + 1 < end; i += 2) {
        int s0 = srcs[i], s1 = srcs[i + 1];
        float n0 = norms[i], n1 = norms[i + 1];
        ushort8v v0 = *reinterpret_cast<const ushort8v*>(&xb[(size_t)s0 * D + cbase]);
        ushort8v v1 = *reinterpret_cast<const ushort8v*>(&xb[(size_t)s1 * D + cbase]);
        #pragma unroll
        for (int j = 0; j < 8; ++j)
            acc[j] += n0 * bf2f(v0[j]) + n1 * bf2f(v1[j]);
    }
    if (i < end) {
        int s0 = srcs[i]; float n0 = norms[i];
        ushort8v v0 = *reinterpret_cast<const ushort8v*>(&xb[(size_t)s0 * D + cbase]);
        #pragma unroll
        for (int j = 0; j < 8; ++j)
            acc[j] += n0 * bf2f(v0[j]);
    }
    float4 o0, o1;
    o0.x = acc[0]; o0.y = acc[1]; o0.z = acc[2]; o0.w = acc[3];
    o1.x = acc[4]; o1.y = acc[5]; o1.z = acc[6]; o1.w = acc[7];
    *reinterpret_cast<float4*>(&outx[(size_t)node * D + cbase]) = o0;
    *reinterpret_cast<float4*>(&outx[(size_t)node * D + cbase + 4]) = o1;
}

// ---------------- fused GEMM (fp32), optional secondary bf16 store ----------------

template<int K, bool RELU, bool HAS_B2, bool HAS_ADD, bool HAS_BIAS, bool STORE_BF16>
__global__ __launch_bounds__(256) void k_gemm(
        const float* __restrict__ A1, const float* __restrict__ W0,
        const float* __restrict__ A2, const float* __restrict__ W1,
        const float* __restrict__ ADDV, const float* __restrict__ bias,
        float* __restrict__ C, unsigned short* __restrict__ Cb, int nrows, int dout) {
    const int BM = 64, BN = 64, BK = 32;
    __shared__ float As[BM][BK + 1];
    __shared__ float Ws[BK][BN];
    int tid = threadIdx.x;
    int tx = tid & 15, ty = tid >> 4;
    int rowBase = blockIdx.x * BM;
    int colBase = blockIdx.y * BN;
    float acc[4][4] = {};

    const int npass = HAS_B2 ? 2 : 1;
    for (int pass = 0; pass < npass; ++pass) {
        const float* A = (pass == 0) ? A1 : A2;
        const float* W = (pass == 0) ? W0 : W1;
        for (int k0 = 0; k0 < K; k0 += BK) {
            #pragma unroll
            for (int l = 0; l < 2; ++l) {
                int f = tid + l * 256;
                int r = f >> 3;
                int j4 = (f & 7) * 4;
                int gr = rowBase + r;
                if (gr >= nrows) gr = nrows - 1;
                float4 v = *reinterpret_cast<const float4*>(&A[(size_t)gr * K + k0 + j4]);
                As[r][j4 + 0] = v.x; As[r][j4 + 1] = v.y;
                As[r][j4 + 2] = v.z; As[r][j4 + 3] = v.w;
            }
            #pragma unroll
            for (int l = 0; l < 2; ++l) {
                int f = tid + l * 256;
                int r = f >> 4;
                int j4 = (f & 15) * 4;
                float4 v = *reinterpret_cast<const float4*>(&W[(size_t)(k0 + r) * dout + colBase + j4]);
                *reinterpret_cast<float4*>(&Ws[r][j4]) = v;
            }
            __syncthreads();
            #pragma unroll
            for (int kk = 0; kk < BK; ++kk) {
                float a[4];
                #pragma unroll
                for (int i = 0; i < 4; ++i) a[i] = As[ty * 4 + i][kk];
                float4 w = *reinterpret_cast<const float4*>(&Ws[kk][tx * 4]);
                float wv[4] = {w.x, w.y, w.z, w.w};
                #pragma unroll
                for (int i = 0; i < 4; ++i)
                    #pragma unroll
                    for (int j = 0; j < 4; ++j)
                        acc[i][j] += a[i] * wv[j];
            }
            __syncthreads();
        }
    }

    #pragma unroll
    for (int i = 0; i < 4; ++i) {
        int r = rowBase + ty * 4 + i;
        if (r < nrows) {
            int cb = colBase + tx * 4;
            float v[4];
            #pragma unroll
            for (int j = 0; j < 4; ++j) v[j] = acc[i][j];
            if (HAS_BIAS) {
                #pragma unroll
                for (int j = 0; j < 4; ++j) v[j] += bias[cb + j];
            }
            if (HAS_ADD) {
                float4 ad = *reinterpret_cast<const float4*>(&ADDV[(size_t)r * dout + cb]);
                v[0] += ad.x; v[1] += ad.y; v[2] += ad.z; v[3] += ad.w;
            }
            if (RELU) {
                #pragma unroll
                for (int j = 0; j < 4; ++j) v[j] = fmaxf(v[j], 0.f);
            }
            float4 o; o.x = v[0]; o.y = v[1]; o.z = v[2]; o.w = v[3];
            *reinterpret_cast<float4*>(&C[(size_t)r * dout + cb]) = o;
            if (STORE_BF16) {
                ushort4v ob;
                #pragma unroll
                for (int j = 0; j < 4; ++j) ob[j] = f2bf(v[j]);
                *reinterpret_cast<ushort4v*>(&Cb[(size_t)r * dout + cb]) = ob;
            }
        }
    }
}

// ---------------- launch ----------------

extern "C" void kernel_launch(void* const* d_in, const int* in_sizes, int n_in,
                              void* d_out, int out_size, void* d_ws, size_t ws_size,
                              hipStream_t stream) {
    const float* x   = (const float*)d_in[0];
    const int*   ei  = (const int*)d_in[1];
    const float* W01 = (const float*)d_in[3];
    const float* W11 = (const float*)d_in[4];
    const float* b1  = (const float*)d_in[5];
    const float* W02 = (const float*)d_in[6];
    const float* W12 = (const float*)d_in[7];
    const float* b2  = (const float*)d_in[8];
    const float* W03 = (const float*)d_in[9];
    const float* W13 = (const float*)d_in[10];
    const float* b3  = (const float*)d_in[11];
    float* out = (float*)d_out;

    const int n = in_sizes[0] / D_IN;   // 10000
    const int E = in_sizes[1] / 2;      // 640000
    const int* src = ei;
    const int* dst = ei + E;

    char* wsb = (char*)d_ws;
    float* dis    = (float*)wsb;                 wsb += 10496 * 4;
    int*   cnt    = (int*)wsb;                   wsb += 10496 * 4;
    int*   off    = (int*)wsb;                   wsb += 10496 * 4;
    int*   cntrun = (int*)wsb;                   wsb += 10496 * 4;
    int*   srcs   = (int*)wsb;                   wsb += (size_t)E * 4;
    float* norms  = (float*)wsb;                 wsb += (size_t)E * 4;
    float* tx     = (float*)wsb;                 wsb += (size_t)n * D_HID * 4;
    float* h1     = (float*)wsb;                 wsb += (size_t)n * D_HID * 4;
    float* h2     = (float*)wsb;                 wsb += (size_t)n * D_HID * 4;
    unsigned short* x_bf  = (unsigned short*)wsb; wsb += (size_t)n * D_IN * 2;
    unsigned short* h1_bf = (unsigned short*)wsb; wsb += (size_t)n * D_HID * 2;
    unsigned short* h2_bf = (unsigned short*)wsb; wsb += (size_t)n * D_HID * 2;
    float* y3    = h1;       // reuse h1 fp32 space after layer 2
    unsigned short* y3_bf = h1_bf;  // reuse h1_bf space after layer-2 aggregate

    const int gx = (n + 63) / 64;

    // ---- normalization + CSR build (dst-sorted edges) + x bf16 ----
    hipMemsetAsync(dis, 0, (size_t)n * sizeof(float), stream);
    hipMemsetAsync(cnt, 0, (size_t)n * sizeof(int), stream);
    k_deg_hist<<<(E + 255) / 256, 256, 0, stream>>>(src, dst, dis, cnt, E);
    k_dis<<<(n + 255) / 256, 256, 0, stream>>>(dis, n);
    k_scan<<<1, 256, 0, stream>>>(cnt, off, cntrun, n, E);
    k_scatter<<<(E + 255) / 256, 256, 0, stream>>>(src, dst, dis, cntrun, srcs, norms, E);
    k_f2bf<<<(n * D_IN / 4 + 255) / 256, 256, 0, stream>>>(x, x_bf, n * D_IN);

    // ---- layer 1: h1 = relu(x@W01 + (A x)@W11 + b1) ----
    k_agg_bf<D_IN, 128><<<dim3((n + 15) / 16, D_IN / 128), 256, 0, stream>>>(
        off, srcs, norms, x_bf, tx, n);
    k_gemm<D_IN, true, true, false, true, true><<<dim3(gx, D_HID / 64), 256, 0, stream>>>(
        x, W01, tx, W11, nullptr, b1, h1, h1_bf, n, D_HID);

    // ---- layer 2: h2 = relu(h1@W02 + (A h1)@W12 + b2) ----
    k_agg_bf<D_HID, 128><<<dim3((n + 15) / 16, D_HID / 128), 256, 0, stream>>>(
        off, srcs, norms, h1_bf, tx, n);
    k_gemm<D_HID, true, true, false, true, true><<<dim3(gx, D_HID / 64), 256, 0, stream>>>(
        h1, W02, tx, W12, nullptr, b2, h2, h2_bf, n, D_HID);

    // ---- layer 3: out = h2@W03 + A (h2@W13) + b3 ----
    k_gemm<D_HID, false, false, false, false, true><<<dim3(gx, D_OUT / 64), 256, 0, stream>>>(
        h2, W13, nullptr, nullptr, nullptr, nullptr, y3, y3_bf, n, D_OUT);
    k_agg_bf<D_OUT, 128><<<dim3((n + 15) / 16, D_OUT / 128), 256, 0, stream>>>(
        off, srcs, norms, y3_bf, tx, n);
    k_gemm<D_HID, false, false, true, true, false><<<dim3(gx, D_OUT / 64), 256, 0, stream>>>(
        h2, W03, nullptr, nullptr, tx, b3, out, nullptr, n, D_OUT);
}

// Round 4
// 244.292 us; speedup vs baseline: 18.1740x; 1.4728x over previous
//
#include <hip/hip_runtime.h>

#define D_IN 128
#define D_HID 256
#define D_OUT 128
#define NBIN 10240          // padded bin count (n=10000)
#define HB 128              // histogram/scatter blocks

typedef __attribute__((ext_vector_type(8))) unsigned short ushort8v;
typedef __attribute__((ext_vector_type(4))) unsigned short ushort4v;
typedef __attribute__((ext_vector_type(8))) short short8v;
typedef __attribute__((ext_vector_type(4))) float f32x4;

__device__ __forceinline__ unsigned short f2bf(float f) {
    unsigned u = __float_as_uint(f);
    unsigned r = (u + 0x7fffu + ((u >> 16) & 1u)) >> 16;
    return (unsigned short)r;
}
__device__ __forceinline__ float bf2f(unsigned short b) {
    return __uint_as_float((unsigned)b << 16);
}

// ---------------- pass A: per-block LDS histograms (no global atomics) ----------------

__global__ __launch_bounds__(256) void k_hist(const int* __restrict__ src, const int* __restrict__ dst,
                                              int* __restrict__ psrc, int* __restrict__ pdst,
                                              int E, int EPB) {
    __shared__ int hs[NBIN];
    __shared__ int hd[NBIN];
    int b = blockIdx.x, t = threadIdx.x;
    for (int i = t; i < NBIN; i += 256) { hs[i] = 0; hd[i] = 0; }
    __syncthreads();
    int beg = b * EPB, end = beg + EPB; if (end > E) end = E;
    for (int e = beg + t; e < end; e += 256) {
        atomicAdd(&hs[src[e]], 1);
        atomicAdd(&hd[dst[e]], 1);
    }
    __syncthreads();
    for (int i = t; i < NBIN; i += 256) {
        psrc[b * NBIN + i] = hs[i];
        pdst[b * NBIN + i] = hd[i];
    }
}

// ---------------- pass B: column sums -> dis, cnt; pdst -> per-block exclusive prefix ----

__global__ __launch_bounds__(256) void k_colsum(const int* __restrict__ psrc, int* __restrict__ pdst,
                                                float* __restrict__ dis, int* __restrict__ cnt) {
    int bin = blockIdx.x * 256 + threadIdx.x;
    if (bin >= NBIN) return;
    int degs = 0;
    for (int b = 0; b < HB; ++b) degs += psrc[b * NBIN + bin];
    int c = 0;
    for (int b = 0; b < HB; ++b) {
        int v = pdst[b * NBIN + bin];
        pdst[b * NBIN + bin] = c;
        c += v;
    }
    dis[bin] = degs > 0 ? rsqrtf((float)degs) : 0.f;
    cnt[bin] = c;
}

// ---------------- exclusive scan (single block) ----------------

__global__ void k_scan(const int* __restrict__ cnt, int* __restrict__ off, int n, int E) {
    __shared__ int sums[256];
    int t = threadIdx.x;
    int chunk = (n + 255) / 256;
    int beg = t * chunk;
    int end = beg + chunk; if (end > n) end = n;
    int s = 0;
    for (int i = beg; i < end; ++i) s += cnt[i];
    sums[t] = s;
    __syncthreads();
    if (t == 0) {
        int running = 0;
        for (int i = 0; i < 256; ++i) { int tmp = sums[i]; sums[i] = running; running += tmp; }
        off[n] = E;
    }
    __syncthreads();
    int pre = sums[t];
    for (int i = beg; i < end; ++i) { off[i] = pre; pre += cnt[i]; }
}

// ---------------- pass C: scatter into dst-sorted order (LDS rank, no global atomics) ----

__global__ __launch_bounds__(256) void k_scatter2(const int* __restrict__ src, const int* __restrict__ dst,
                                                  const float* __restrict__ dis, const int* __restrict__ off,
                                                  const int* __restrict__ pfx,
                                                  int* __restrict__ srcs, float* __restrict__ norms,
                                                  int E, int EPB) {
    __shared__ int lcnt[NBIN];
    int b = blockIdx.x, t = threadIdx.x;
    for (int i = t; i < NBIN; i += 256) lcnt[i] = 0;
    __syncthreads();
    int beg = b * EPB, end = beg + EPB; if (end > E) end = E;
    const int* pf = pfx + b * NBIN;
    for (int e = beg + t; e < end; e += 256) {
        int s = src[e], d = dst[e];
        int r = atomicAdd(&lcnt[d], 1);    // LDS atomic only
        int pos = off[d] + pf[d] + r;
        srcs[pos] = s;
        norms[pos] = -(dis[s] * dis[d]);
    }
}

// ---------------- fp32 -> bf16 convert ----------------

__global__ void k_f2bf(const float* __restrict__ in, unsigned short* __restrict__ out, int nElem) {
    int i = (blockIdx.x * blockDim.x + threadIdx.x) * 4;
    if (i < nElem) {
        float4 v = *reinterpret_cast<const float4*>(&in[i]);
        ushort4v o;
        o[0] = f2bf(v.x); o[1] = f2bf(v.y); o[2] = f2bf(v.z); o[3] = f2bf(v.w);
        *reinterpret_cast<ushort4v*>(&out[i]) = o;
    }
}

// ---------------- weight transpose + convert: W[K][N] f32 -> Wt[N][K] bf16 ----------------

__global__ __launch_bounds__(256) void k_wtr(const float* __restrict__ W, unsigned short* __restrict__ Wt,
                                             int K, int N) {
    __shared__ float tile[32][33];
    int k0 = blockIdx.x * 32, n0 = blockIdx.y * 32;
    int tx = threadIdx.x & 31, ty = threadIdx.x >> 5;   // 32x8
    for (int i = ty; i < 32; i += 8) tile[i][tx] = W[(size_t)(k0 + i) * N + n0 + tx];
    __syncthreads();
    for (int i = ty; i < 32; i += 8) Wt[(size_t)(n0 + i) * K + k0 + tx] = f2bf(tile[tx][i]);
}

// ---------------- CSR gather-aggregate, bf16 input, column-chunked ----------------

template<int D, bool STBF, bool STF32>
__global__ __launch_bounds__(256) void k_agg_bf(const int* __restrict__ off,
                                                const int* __restrict__ srcs,
                                                const float* __restrict__ norms,
                                                const unsigned short* __restrict__ xb,
                                                unsigned short* __restrict__ outb,
                                                float* __restrict__ outf, int n) {
    const int CHUNK = 128;
    const int TPN = CHUNK / 8;       // 16 lanes per node
    const int NPB = 256 / TPN;       // 16 nodes per block
    int tid = threadIdx.x;
    int node = blockIdx.x * NPB + tid / TPN;
    if (node >= n) return;
    int cbase = blockIdx.y * CHUNK + (tid % TPN) * 8;
    int i = off[node], end = off[node + 1];
    float acc[8] = {};
    for (; i + 1 < end; i += 2) {
        int s0 = srcs[i], s1 = srcs[i + 1];
        float n0 = norms[i], n1 = norms[i + 1];
        ushort8v v0 = *reinterpret_cast<const ushort8v*>(&xb[(size_t)s0 * D + cbase]);
        ushort8v v1 = *reinterpret_cast<const ushort8v*>(&xb[(size_t)s1 * D + cbase]);
        #pragma unroll
        for (int j = 0; j < 8; ++j)
            acc[j] += n0 * bf2f(v0[j]) + n1 * bf2f(v1[j]);
    }
    if (i < end) {
        int s0 = srcs[i]; float n0 = norms[i];
        ushort8v v0 = *reinterpret_cast<const ushort8v*>(&xb[(size_t)s0 * D + cbase]);
        #pragma unroll
        for (int j = 0; j < 8; ++j)
            acc[j] += n0 * bf2f(v0[j]);
    }
    if (STBF) {
        ushort8v ob;
        #pragma unroll
        for (int j = 0; j < 8; ++j) ob[j] = f2bf(acc[j]);
        *reinterpret_cast<ushort8v*>(&outb[(size_t)node * D + cbase]) = ob;
    }
    if (STF32) {
        float4 o0, o1;
        o0.x = acc[0]; o0.y = acc[1]; o0.z = acc[2]; o0.w = acc[3];
        o1.x = acc[4]; o1.y = acc[5]; o1.z = acc[6]; o1.w = acc[7];
        *reinterpret_cast<float4*>(&outf[(size_t)node * D + cbase]) = o0;
        *reinterpret_cast<float4*>(&outf[(size_t)node * D + cbase + 4]) = o1;
    }
}

// ---------------- MFMA bf16 GEMM ----------------
// C[M,N] = epi( A1@W0t' (+ A2@W1t') ), A:[M][K] bf16, Wt:[N][K] bf16.
// 128x128 tile, 4 waves (2x2), 16x16x32 MFMA, fp32 accum.

template<int K, bool RELU, bool HAS_B2, bool HAS_ADD, bool HAS_BIAS, bool ST_BF, bool ST_F32>
__global__ __launch_bounds__(256) void k_gemm_mfma(
        const unsigned short* __restrict__ A1, const unsigned short* __restrict__ W0t,
        const unsigned short* __restrict__ A2, const unsigned short* __restrict__ W1t,
        const float* __restrict__ ADDV, const float* __restrict__ bias,
        float* __restrict__ C, unsigned short* __restrict__ Cb, int M, int N) {
    const int LDT = 40;                       // lds row stride (bf16), padded
    __shared__ unsigned short As[128 * LDT];
    __shared__ unsigned short Bs[128 * LDT];
    int tid = threadIdx.x, lane = tid & 63, wave = tid >> 6;
    int wm = wave >> 1, wn = wave & 1;
    int row0 = blockIdx.x * 128, col0 = blockIdx.y * 128;
    f32x4 acc[4][4];
    #pragma unroll
    for (int i = 0; i < 4; ++i)
        #pragma unroll
        for (int j = 0; j < 4; ++j)
            acc[i][j] = (f32x4){0.f, 0.f, 0.f, 0.f};

    int aRow = wm * 64 + (lane & 15);
    int bRow = wn * 64 + (lane & 15);
    int kOff = (lane >> 4) * 8;

    const int npass = HAS_B2 ? 2 : 1;
    for (int pass = 0; pass < npass; ++pass) {
        const unsigned short* A = pass ? A2 : A1;
        const unsigned short* W = pass ? W1t : W0t;
        for (int k0 = 0; k0 < K; k0 += 32) {
            int f = tid;
            #pragma unroll
            for (int l = 0; l < 2; ++l, f += 256) {
                int r = f >> 2, c = (f & 3) * 8;
                int gr = row0 + r; if (gr >= M) gr = M - 1;
                ushort8v va = *reinterpret_cast<const ushort8v*>(&A[(size_t)gr * K + k0 + c]);
                *reinterpret_cast<ushort8v*>(&As[r * LDT + c]) = va;
                ushort8v vb = *reinterpret_cast<const ushort8v*>(&W[(size_t)(col0 + r) * K + k0 + c]);
                *reinterpret_cast<ushort8v*>(&Bs[r * LDT + c]) = vb;
            }
            __syncthreads();
            short8v a[4], bb[4];
            #pragma unroll
            for (int i = 0; i < 4; ++i) {
                a[i]  = *reinterpret_cast<const short8v*>(&As[(aRow + i * 16) * LDT + kOff]);
                bb[i] = *reinterpret_cast<const short8v*>(&Bs[(bRow + i * 16) * LDT + kOff]);
            }
            #pragma unroll
            for (int mi = 0; mi < 4; ++mi)
                #pragma unroll
                for (int ni = 0; ni < 4; ++ni)
                    acc[mi][ni] = __builtin_amdgcn_mfma_f32_16x16x32_bf16(a[mi], bb[ni], acc[mi][ni], 0, 0, 0);
            __syncthreads();
        }
    }

    // epilogue: C/D layout col = lane&15, row = (lane>>4)*4 + reg
    int colBase = col0 + wn * 64 + (lane & 15);
    int rowSub = (lane >> 4) * 4;
    #pragma unroll
    for (int mi = 0; mi < 4; ++mi) {
        int rowF = row0 + wm * 64 + mi * 16 + rowSub;
        #pragma unroll
        for (int r = 0; r < 4; ++r) {
            int gr = rowF + r;
            if (gr < M) {
                #pragma unroll
                for (int ni = 0; ni < 4; ++ni) {
                    int gc = colBase + ni * 16;
                    float v = acc[mi][ni][r];
                    if (HAS_BIAS) v += bias[gc];
                    if (HAS_ADD)  v += ADDV[(size_t)gr * N + gc];
                    if (RELU)     v = fmaxf(v, 0.f);
                    if (ST_F32)   C[(size_t)gr * N + gc] = v;
                    if (ST_BF)    Cb[(size_t)gr * N + gc] = f2bf(v);
                }
            }
        }
    }
}

// ---------------- launch ----------------

extern "C" void kernel_launch(void* const* d_in, const int* in_sizes, int n_in,
                              void* d_out, int out_size, void* d_ws, size_t ws_size,
                              hipStream_t stream) {
    const float* x   = (const float*)d_in[0];
    const int*   ei  = (const int*)d_in[1];
    const float* W01 = (const float*)d_in[3];
    const float* W11 = (const float*)d_in[4];
    const float* b1  = (const float*)d_in[5];
    const float* W02 = (const float*)d_in[6];
    const float* W12 = (const float*)d_in[7];
    const float* b2  = (const float*)d_in[8];
    const float* W03 = (const float*)d_in[9];
    const float* W13 = (const float*)d_in[10];
    const float* b3  = (const float*)d_in[11];
    float* out = (float*)d_out;

    const int n = in_sizes[0] / D_IN;   // 10000
    const int E = in_sizes[1] / 2;      // 640000
    const int* src = ei;
    const int* dst = ei + E;
    const int EPB = (E + HB - 1) / HB;  // 5000

    char* wsb = (char*)d_ws;
    float* dis   = (float*)wsb;                   wsb += NBIN * 4;
    int*   cnt   = (int*)wsb;                     wsb += NBIN * 4;
    int*   off   = (int*)wsb;                     wsb += (NBIN + 16) * 4;
    int*   psrc  = (int*)wsb;                     wsb += (size_t)HB * NBIN * 4;
    int*   pdst  = (int*)wsb;                     wsb += (size_t)HB * NBIN * 4;
    int*   srcs  = (int*)wsb;                     wsb += (size_t)E * 4;
    float* norms = (float*)wsb;                   wsb += (size_t)E * 4;
    unsigned short* txb  = (unsigned short*)wsb;  wsb += (size_t)n * D_HID * 2;
    float*          tx32 = (float*)wsb;           wsb += (size_t)n * D_OUT * 4;
    unsigned short* x_bf = (unsigned short*)wsb;  wsb += (size_t)n * D_IN * 2;
    unsigned short* h1_bf = (unsigned short*)wsb; wsb += (size_t)n * D_HID * 2;
    unsigned short* h2_bf = (unsigned short*)wsb; wsb += (size_t)n * D_HID * 2;
    unsigned short* y3_bf = (unsigned short*)wsb; wsb += (size_t)n * D_OUT * 2;
    unsigned short* W01t = (unsigned short*)wsb;  wsb += (size_t)D_IN  * D_HID * 2;
    unsigned short* W11t = (unsigned short*)wsb;  wsb += (size_t)D_IN  * D_HID * 2;
    unsigned short* W02t = (unsigned short*)wsb;  wsb += (size_t)D_HID * D_HID * 2;
    unsigned short* W12t = (unsigned short*)wsb;  wsb += (size_t)D_HID * D_HID * 2;
    unsigned short* W03t = (unsigned short*)wsb;  wsb += (size_t)D_HID * D_OUT * 2;
    unsigned short* W13t = (unsigned short*)wsb;  wsb += (size_t)D_HID * D_OUT * 2;

    const int gmx = (n + 127) / 128;    // 79 M-tiles

    // ---- CSR build (atomic-free) + normalization ----
    k_hist<<<HB, 256, 0, stream>>>(src, dst, psrc, pdst, E, EPB);
    k_colsum<<<NBIN / 256, 256, 0, stream>>>(psrc, pdst, dis, cnt);
    k_scan<<<1, 256, 0, stream>>>(cnt, off, n, E);
    k_scatter2<<<HB, 256, 0, stream>>>(src, dst, dis, off, pdst, srcs, norms, E, EPB);

    // ---- bf16 conversions ----
    k_f2bf<<<(n * D_IN / 4 + 255) / 256, 256, 0, stream>>>(x, x_bf, n * D_IN);
    k_wtr<<<dim3(D_IN / 32,  D_HID / 32), 256, 0, stream>>>(W01, W01t, D_IN,  D_HID);
    k_wtr<<<dim3(D_IN / 32,  D_HID / 32), 256, 0, stream>>>(W11, W11t, D_IN,  D_HID);
    k_wtr<<<dim3(D_HID / 32, D_HID / 32), 256, 0, stream>>>(W02, W02t, D_HID, D_HID);
    k_wtr<<<dim3(D_HID / 32, D_HID / 32), 256, 0, stream>>>(W12, W12t, D_HID, D_HID);
    k_wtr<<<dim3(D_HID / 32, D_OUT / 32), 256, 0, stream>>>(W03, W03t, D_HID, D_OUT);
    k_wtr<<<dim3(D_HID / 32, D_OUT / 32), 256, 0, stream>>>(W13, W13t, D_HID, D_OUT);

    // ---- layer 1: h1 = relu(x@W01 + (A x)@W11 + b1) ----
    k_agg_bf<D_IN, true, false><<<dim3((n + 15) / 16, 1), 256, 0, stream>>>(
        off, srcs, norms, x_bf, txb, nullptr, n);
    k_gemm_mfma<D_IN, true, true, false, true, true, false><<<dim3(gmx, D_HID / 128), 256, 0, stream>>>(
        x_bf, W01t, txb, W11t, nullptr, b1, nullptr, h1_bf, n, D_HID);

    // ---- layer 2: h2 = relu(h1@W02 + (A h1)@W12 + b2) ----
    k_agg_bf<D_HID, true, false><<<dim3((n + 15) / 16, 2), 256, 0, stream>>>(
        off, srcs, norms, h1_bf, txb, nullptr, n);
    k_gemm_mfma<D_HID, true, true, false, true, true, false><<<dim3(gmx, D_HID / 128), 256, 0, stream>>>(
        h1_bf, W02t, txb, W12t, nullptr, b2, nullptr, h2_bf, n, D_HID);

    // ---- layer 3: out = h2@W03 + A (h2@W13) + b3 ----
    k_gemm_mfma<D_HID, false, false, false, false, true, false><<<dim3(gmx, D_OUT / 128), 256, 0, stream>>>(
        h2_bf, W13t, nullptr, nullptr, nullptr, nullptr, nullptr, y3_bf, n, D_OUT);
    k_agg_bf<D_OUT, false, true><<<dim3((n + 15) / 16, 1), 256, 0, stream>>>(
        off, srcs, norms, y3_bf, nullptr, tx32, n);
    k_gemm_mfma<D_HID, false, false, true, true, false, true><<<dim3(gmx, D_OUT / 128), 256, 0, stream>>>(
        h2_bf, W03t, nullptr, nullptr, tx32, b3, out, nullptr, n, D_OUT);
}

// Round 5
// 211.707 us; speedup vs baseline: 20.9712x; 1.1539x over previous
//
#include <hip/hip_runtime.h>

#define D_IN 128
#define D_HID 256
#define D_OUT 128
#define NBIN 10240          // padded bin count (n=10000)
#define HB 128              // histogram/scatter blocks

typedef __attribute__((ext_vector_type(8))) unsigned short ushort8v;
typedef __attribute__((ext_vector_type(4))) unsigned short ushort4v;
typedef __attribute__((ext_vector_type(8))) short short8v;
typedef __attribute__((ext_vector_type(4))) float f32x4;

__device__ __forceinline__ unsigned short f2bf(float f) {
    unsigned u = __float_as_uint(f);
    unsigned r = (u + 0x7fffu + ((u >> 16) & 1u)) >> 16;
    return (unsigned short)r;
}
__device__ __forceinline__ float bf2f(unsigned short b) {
    return __uint_as_float((unsigned)b << 16);
}

// ---------------- pass A: per-block LDS histograms (no global atomics) ----------------

__global__ __launch_bounds__(256) void k_hist(const int* __restrict__ src, const int* __restrict__ dst,
                                              int* __restrict__ psrc, int* __restrict__ pdst,
                                              int E, int EPB) {
    __shared__ int hs[NBIN];
    __shared__ int hd[NBIN];
    int b = blockIdx.x, t = threadIdx.x;
    for (int i = t; i < NBIN; i += 256) { hs[i] = 0; hd[i] = 0; }
    __syncthreads();
    int beg = b * EPB, end = beg + EPB; if (end > E) end = E;
    for (int e = beg + t; e < end; e += 256) {
        atomicAdd(&hs[src[e]], 1);
        atomicAdd(&hd[dst[e]], 1);
    }
    __syncthreads();
    for (int i = t; i < NBIN; i += 256) {
        psrc[b * NBIN + i] = hs[i];
        pdst[b * NBIN + i] = hd[i];
    }
}

// ---------------- pass B: column sums -> dis, cnt; pdst -> per-block exclusive prefix ----

__global__ __launch_bounds__(256) void k_colsum(const int* __restrict__ psrc, int* __restrict__ pdst,
                                                float* __restrict__ dis, int* __restrict__ cnt) {
    int bin = blockIdx.x * 256 + threadIdx.x;
    if (bin >= NBIN) return;
    int degs = 0;
    for (int b = 0; b < HB; ++b) degs += psrc[b * NBIN + bin];
    int c = 0;
    for (int b = 0; b < HB; ++b) {
        int v = pdst[b * NBIN + bin];
        pdst[b * NBIN + bin] = c;
        c += v;
    }
    dis[bin] = degs > 0 ? rsqrtf((float)degs) : 0.f;
    cnt[bin] = c;
}

// ---------------- exclusive scan (single block) ----------------

__global__ void k_scan(const int* __restrict__ cnt, int* __restrict__ off, int n, int E) {
    __shared__ int sums[256];
    int t = threadIdx.x;
    int chunk = (n + 255) / 256;
    int beg = t * chunk;
    int end = beg + chunk; if (end > n) end = n;
    int s = 0;
    for (int i = beg; i < end; ++i) s += cnt[i];
    sums[t] = s;
    __syncthreads();
    if (t == 0) {
        int running = 0;
        for (int i = 0; i < 256; ++i) { int tmp = sums[i]; sums[i] = running; running += tmp; }
        off[n] = E;
    }
    __syncthreads();
    int pre = sums[t];
    for (int i = beg; i < end; ++i) { off[i] = pre; pre += cnt[i]; }
}

// ---------------- pass C: scatter into dst-sorted order (LDS rank, no global atomics) ----

__global__ __launch_bounds__(256) void k_scatter2(const int* __restrict__ src, const int* __restrict__ dst,
                                                  const float* __restrict__ dis, const int* __restrict__ off,
                                                  const int* __restrict__ pfx,
                                                  int* __restrict__ srcs, float* __restrict__ norms,
                                                  int E, int EPB) {
    __shared__ int lcnt[NBIN];
    int b = blockIdx.x, t = threadIdx.x;
    for (int i = t; i < NBIN; i += 256) lcnt[i] = 0;
    __syncthreads();
    int beg = b * EPB, end = beg + EPB; if (end > E) end = E;
    const int* pf = pfx + b * NBIN;
    for (int e = beg + t; e < end; e += 256) {
        int s = src[e], d = dst[e];
        int r = atomicAdd(&lcnt[d], 1);    // LDS atomic only
        int pos = off[d] + pf[d] + r;
        srcs[pos] = s;
        norms[pos] = -(dis[s] * dis[d]);
    }
}

// ---------------- fp32 -> bf16 convert ----------------

__global__ void k_f2bf(const float* __restrict__ in, unsigned short* __restrict__ out, int nElem) {
    int i = (blockIdx.x * blockDim.x + threadIdx.x) * 4;
    if (i < nElem) {
        float4 v = *reinterpret_cast<const float4*>(&in[i]);
        ushort4v o;
        o[0] = f2bf(v.x); o[1] = f2bf(v.y); o[2] = f2bf(v.z); o[3] = f2bf(v.w);
        *reinterpret_cast<ushort4v*>(&out[i]) = o;
    }
}

// ---------------- 6 weight transposes in one dispatch ----------------
// W[K][N] f32 -> Wt[N][K] bf16, z selects which matrix.

struct WtrArgs {
    const float* W[6];
    unsigned short* T[6];
    int K[6];
    int N[6];
};

__global__ __launch_bounds__(256) void k_wtr6(WtrArgs args) {
    __shared__ float tile[32][33];
    int z = blockIdx.z;
    const float* W = args.W[z];
    unsigned short* Wt = args.T[z];
    int K = args.K[z], N = args.N[z];
    int k0 = blockIdx.x * 32, n0 = blockIdx.y * 32;
    if (k0 >= K || n0 >= N) return;
    int tx = threadIdx.x & 31, ty = threadIdx.x >> 5;   // 32x8
    for (int i = ty; i < 32; i += 8) tile[i][tx] = W[(size_t)(k0 + i) * N + n0 + tx];
    __syncthreads();
    for (int i = ty; i < 32; i += 8) Wt[(size_t)(n0 + i) * K + k0 + tx] = f2bf(tile[tx][i]);
}

// ---------------- CSR gather-aggregate, bf16 input, column-chunked, ILP-4 ----------------

template<int D, bool STBF, bool STF32>
__global__ __launch_bounds__(256) void k_agg_bf(const int* __restrict__ off,
                                                const int* __restrict__ srcs,
                                                const float* __restrict__ norms,
                                                const unsigned short* __restrict__ xb,
                                                unsigned short* __restrict__ outb,
                                                float* __restrict__ outf, int n) {
    const int CHUNK = 128;
    const int TPN = CHUNK / 8;       // 16 lanes per node
    const int NPB = 256 / TPN;       // 16 nodes per block
    int tid = threadIdx.x;
    int node = blockIdx.x * NPB + tid / TPN;
    if (node >= n) return;
    int cbase = blockIdx.y * CHUNK + (tid % TPN) * 8;
    int i = off[node], end = off[node + 1];
    float acc[8] = {};
    for (; i + 3 < end; i += 4) {
        int s0 = srcs[i], s1 = srcs[i + 1], s2 = srcs[i + 2], s3 = srcs[i + 3];
        float n0 = norms[i], n1 = norms[i + 1], n2 = norms[i + 2], n3 = norms[i + 3];
        ushort8v v0 = *reinterpret_cast<const ushort8v*>(&xb[(size_t)s0 * D + cbase]);
        ushort8v v1 = *reinterpret_cast<const ushort8v*>(&xb[(size_t)s1 * D + cbase]);
        ushort8v v2 = *reinterpret_cast<const ushort8v*>(&xb[(size_t)s2 * D + cbase]);
        ushort8v v3 = *reinterpret_cast<const ushort8v*>(&xb[(size_t)s3 * D + cbase]);
        #pragma unroll
        for (int j = 0; j < 8; ++j)
            acc[j] += (n0 * bf2f(v0[j]) + n1 * bf2f(v1[j]))
                    + (n2 * bf2f(v2[j]) + n3 * bf2f(v3[j]));
    }
    for (; i < end; ++i) {
        int s0 = srcs[i]; float n0 = norms[i];
        ushort8v v0 = *reinterpret_cast<const ushort8v*>(&xb[(size_t)s0 * D + cbase]);
        #pragma unroll
        for (int j = 0; j < 8; ++j)
            acc[j] += n0 * bf2f(v0[j]);
    }
    if (STBF) {
        ushort8v ob;
        #pragma unroll
        for (int j = 0; j < 8; ++j) ob[j] = f2bf(acc[j]);
        *reinterpret_cast<ushort8v*>(&outb[(size_t)node * D + cbase]) = ob;
    }
    if (STF32) {
        float4 o0, o1;
        o0.x = acc[0]; o0.y = acc[1]; o0.z = acc[2]; o0.w = acc[3];
        o1.x = acc[4]; o1.y = acc[5]; o1.z = acc[6]; o1.w = acc[7];
        *reinterpret_cast<float4*>(&outf[(size_t)node * D + cbase]) = o0;
        *reinterpret_cast<float4*>(&outf[(size_t)node * D + cbase + 4]) = o1;
    }
}

// ---------------- MFMA bf16 GEMM ----------------
// C[M,N] = epi( A1@W0t' (+ A2@W1t') ), A:[M][K] bf16, Wt:[N][K] bf16.
// BM=64 x BN=128 tile, 4 waves (2x2), each wave 32x64, 16x16x32 MFMA, fp32 accum.

template<int K, bool RELU, bool HAS_B2, bool HAS_ADD, bool HAS_BIAS, bool ST_BF, bool ST_F32>
__global__ __launch_bounds__(256) void k_gemm_mfma(
        const unsigned short* __restrict__ A1, const unsigned short* __restrict__ W0t,
        const unsigned short* __restrict__ A2, const unsigned short* __restrict__ W1t,
        const float* __restrict__ ADDV, const float* __restrict__ bias,
        float* __restrict__ C, unsigned short* __restrict__ Cb, int M, int N) {
    const int LDT = 40;                       // lds row stride (bf16), padded
    __shared__ unsigned short As[64 * LDT];
    __shared__ unsigned short Bs[128 * LDT];
    int tid = threadIdx.x, lane = tid & 63, wave = tid >> 6;
    int wm = wave >> 1, wn = wave & 1;
    int row0 = blockIdx.x * 64, col0 = blockIdx.y * 128;
    f32x4 acc[2][4];
    #pragma unroll
    for (int i = 0; i < 2; ++i)
        #pragma unroll
        for (int j = 0; j < 4; ++j)
            acc[i][j] = (f32x4){0.f, 0.f, 0.f, 0.f};

    int aRow = wm * 32 + (lane & 15);
    int bRow = wn * 64 + (lane & 15);
    int kOff = (lane >> 4) * 8;

    const int npass = HAS_B2 ? 2 : 1;
    for (int pass = 0; pass < npass; ++pass) {
        const unsigned short* A = pass ? A2 : A1;
        const unsigned short* W = pass ? W1t : W0t;
        for (int k0 = 0; k0 < K; k0 += 32) {
            {   // stage A: 64 rows x 32 k, 1 ushort8 per thread
                int r = tid >> 2, c = (tid & 3) * 8;
                int gr = row0 + r; if (gr >= M) gr = M - 1;
                ushort8v va = *reinterpret_cast<const ushort8v*>(&A[(size_t)gr * K + k0 + c]);
                *reinterpret_cast<ushort8v*>(&As[r * LDT + c]) = va;
            }
            {   // stage B: 128 rows x 32 k, 2 ushort8 per thread
                int f = tid;
                #pragma unroll
                for (int l = 0; l < 2; ++l, f += 256) {
                    int r = f >> 2, c = (f & 3) * 8;
                    ushort8v vb = *reinterpret_cast<const ushort8v*>(&W[(size_t)(col0 + r) * K + k0 + c]);
                    *reinterpret_cast<ushort8v*>(&Bs[r * LDT + c]) = vb;
                }
            }
            __syncthreads();
            short8v a[2], bb[4];
            #pragma unroll
            for (int i = 0; i < 2; ++i)
                a[i] = *reinterpret_cast<const short8v*>(&As[(aRow + i * 16) * LDT + kOff]);
            #pragma unroll
            for (int i = 0; i < 4; ++i)
                bb[i] = *reinterpret_cast<const short8v*>(&Bs[(bRow + i * 16) * LDT + kOff]);
            #pragma unroll
            for (int mi = 0; mi < 2; ++mi)
                #pragma unroll
                for (int ni = 0; ni < 4; ++ni)
                    acc[mi][ni] = __builtin_amdgcn_mfma_f32_16x16x32_bf16(a[mi], bb[ni], acc[mi][ni], 0, 0, 0);
            __syncthreads();
        }
    }

    // epilogue: C/D layout col = lane&15, row = (lane>>4)*4 + reg
    int colBase = col0 + wn * 64 + (lane & 15);
    int rowSub = (lane >> 4) * 4;
    #pragma unroll
    for (int mi = 0; mi < 2; ++mi) {
        int rowF = row0 + wm * 32 + mi * 16 + rowSub;
        #pragma unroll
        for (int r = 0; r < 4; ++r) {
            int gr = rowF + r;
            if (gr < M) {
                #pragma unroll
                for (int ni = 0; ni < 4; ++ni) {
                    int gc = colBase + ni * 16;
                    float v = acc[mi][ni][r];
                    if (HAS_BIAS) v += bias[gc];
                    if (HAS_ADD)  v += ADDV[(size_t)gr * N + gc];
                    if (RELU)     v = fmaxf(v, 0.f);
                    if (ST_F32)   C[(size_t)gr * N + gc] = v;
                    if (ST_BF)    Cb[(size_t)gr * N + gc] = f2bf(v);
                }
            }
        }
    }
}

// ---------------- launch ----------------

extern "C" void kernel_launch(void* const* d_in, const int* in_sizes, int n_in,
                              void* d_out, int out_size, void* d_ws, size_t ws_size,
                              hipStream_t stream) {
    const float* x   = (const float*)d_in[0];
    const int*   ei  = (const int*)d_in[1];
    const float* W01 = (const float*)d_in[3];
    const float* W11 = (const float*)d_in[4];
    const float* b1  = (const float*)d_in[5];
    const float* W02 = (const float*)d_in[6];
    const float* W12 = (const float*)d_in[7];
    const float* b2  = (const float*)d_in[8];
    const float* W03 = (const float*)d_in[9];
    const float* W13 = (const float*)d_in[10];
    const float* b3  = (const float*)d_in[11];
    float* out = (float*)d_out;

    const int n = in_sizes[0] / D_IN;   // 10000
    const int E = in_sizes[1] / 2;      // 640000
    const int* src = ei;
    const int* dst = ei + E;
    const int EPB = (E + HB - 1) / HB;  // 5000

    char* wsb = (char*)d_ws;
    float* dis   = (float*)wsb;                   wsb += NBIN * 4;
    int*   cnt   = (int*)wsb;                     wsb += NBIN * 4;
    int*   off   = (int*)wsb;                     wsb += (NBIN + 16) * 4;
    int*   psrc  = (int*)wsb;                     wsb += (size_t)HB * NBIN * 4;
    int*   pdst  = (int*)wsb;                     wsb += (size_t)HB * NBIN * 4;
    int*   srcs  = (int*)wsb;                     wsb += (size_t)E * 4;
    float* norms = (float*)wsb;                   wsb += (size_t)E * 4;
    unsigned short* txb  = (unsigned short*)wsb;  wsb += (size_t)n * D_HID * 2;
    float*          tx32 = (float*)wsb;           wsb += (size_t)n * D_OUT * 4;
    unsigned short* x_bf = (unsigned short*)wsb;  wsb += (size_t)n * D_IN * 2;
    unsigned short* h1_bf = (unsigned short*)wsb; wsb += (size_t)n * D_HID * 2;
    unsigned short* h2_bf = (unsigned short*)wsb; wsb += (size_t)n * D_HID * 2;
    unsigned short* y3_bf = (unsigned short*)wsb; wsb += (size_t)n * D_OUT * 2;
    unsigned short* W01t = (unsigned short*)wsb;  wsb += (size_t)D_IN  * D_HID * 2;
    unsigned short* W11t = (unsigned short*)wsb;  wsb += (size_t)D_IN  * D_HID * 2;
    unsigned short* W02t = (unsigned short*)wsb;  wsb += (size_t)D_HID * D_HID * 2;
    unsigned short* W12t = (unsigned short*)wsb;  wsb += (size_t)D_HID * D_HID * 2;
    unsigned short* W03t = (unsigned short*)wsb;  wsb += (size_t)D_HID * D_OUT * 2;
    unsigned short* W13t = (unsigned short*)wsb;  wsb += (size_t)D_HID * D_OUT * 2;

    const int gmx = (n + 63) / 64;      // 157 M-tiles

    // ---- CSR build (atomic-free) + normalization ----
    k_hist<<<HB, 256, 0, stream>>>(src, dst, psrc, pdst, E, EPB);
    k_colsum<<<NBIN / 256, 256, 0, stream>>>(psrc, pdst, dis, cnt);
    k_scan<<<1, 256, 0, stream>>>(cnt, off, n, E);
    k_scatter2<<<HB, 256, 0, stream>>>(src, dst, dis, off, pdst, srcs, norms, E, EPB);

    // ---- bf16 conversions ----
    k_f2bf<<<(n * D_IN / 4 + 255) / 256, 256, 0, stream>>>(x, x_bf, n * D_IN);
    {
        WtrArgs wa;
        wa.W[0] = W01; wa.T[0] = W01t; wa.K[0] = D_IN;  wa.N[0] = D_HID;
        wa.W[1] = W11; wa.T[1] = W11t; wa.K[1] = D_IN;  wa.N[1] = D_HID;
        wa.W[2] = W02; wa.T[2] = W02t; wa.K[2] = D_HID; wa.N[2] = D_HID;
        wa.W[3] = W12; wa.T[3] = W12t; wa.K[3] = D_HID; wa.N[3] = D_HID;
        wa.W[4] = W03; wa.T[4] = W03t; wa.K[4] = D_HID; wa.N[4] = D_OUT;
        wa.W[5] = W13; wa.T[5] = W13t; wa.K[5] = D_HID; wa.N[5] = D_OUT;
        k_wtr6<<<dim3(8, 8, 6), 256, 0, stream>>>(wa);
    }

    // ---- layer 1: h1 = relu(x@W01 + (A x)@W11 + b1) ----
    k_agg_bf<D_IN, true, false><<<dim3((n + 15) / 16, 1), 256, 0, stream>>>(
        off, srcs, norms, x_bf, txb, nullptr, n);
    k_gemm_mfma<D_IN, true, true, false, true, true, false><<<dim3(gmx, D_HID / 128), 256, 0, stream>>>(
        x_bf, W01t, txb, W11t, nullptr, b1, nullptr, h1_bf, n, D_HID);

    // ---- layer 2: h2 = relu(h1@W02 + (A h1)@W12 + b2) ----
    k_agg_bf<D_HID, true, false><<<dim3((n + 15) / 16, 2), 256, 0, stream>>>(
        off, srcs, norms, h1_bf, txb, nullptr, n);
    k_gemm_mfma<D_HID, true, true, false, true, true, false><<<dim3(gmx, D_HID / 128), 256, 0, stream>>>(
        h1_bf, W02t, txb, W12t, nullptr, b2, nullptr, h2_bf, n, D_HID);

    // ---- layer 3: out = h2@W03 + A (h2@W13) + b3 ----
    k_gemm_mfma<D_HID, false, false, false, false, true, false><<<dim3(gmx, D_OUT / 128), 256, 0, stream>>>(
        h2_bf, W13t, nullptr, nullptr, nullptr, nullptr, nullptr, y3_bf, n, D_OUT);
    k_agg_bf<D_OUT, false, true><<<dim3((n + 15) / 16, 1), 256, 0, stream>>>(
        off, srcs, norms, y3_bf, nullptr, tx32, n);
    k_gemm_mfma<D_HID, false, false, true, true, false, true><<<dim3(gmx, D_OUT / 128), 256, 0, stream>>>(
        h2_bf, W03t, nullptr, nullptr, tx32, b3, out, nullptr, n, D_OUT);
}